// Round 13
// baseline (253.908 us; speedup 1.0000x reference)
//
#include <hip/hip_runtime.h>
#include <stdint.h>

// MultiHeadSelfAttention: E=1024, H=16, S=4096, half=512, Dh=32, scale=sqrt(64)=8
// Inputs fp32. R11 structure (best: 194.5us): convert_w -> qkv (x inline-cvt)
// -> split-K attn -> combine -> outproj. R13: attn reads K fragments directly
// from global (L1-broadcast across waves) -- Ks LDS tile deleted.

#define SEQ    4096
#define DMODEL 1024
#define DHALF  512
#define NH     16
#define DH     32

typedef __attribute__((ext_vector_type(4))) float facc4;
typedef __attribute__((ext_vector_type(8))) short bfrag8;

#define MFMA_BF16(a, b, c) __builtin_amdgcn_mfma_f32_16x16x32_bf16((a), (b), (c), 0, 0, 0)

static __device__ __forceinline__ uint16_t f2b(float x) {
    uint32_t u = __float_as_uint(x);
    return (uint16_t)((u + 0x7FFFu + ((u >> 16) & 1u)) >> 16);  // RNE
}
static __device__ __forceinline__ float b2f(uint16_t b) {
    return __uint_as_float(((uint32_t)b) << 16);
}

// 8x fp32 -> 8x bf16 (round-half-away; ties measure-small) via 2add+1perm pairs
static __device__ __forceinline__ bfrag8 cvt8perm(float4 a, float4 b) {
    uint32_t u0 = __float_as_uint(a.x) + 0x8000u, u1 = __float_as_uint(a.y) + 0x8000u;
    uint32_t u2 = __float_as_uint(a.z) + 0x8000u, u3 = __float_as_uint(a.w) + 0x8000u;
    uint32_t u4 = __float_as_uint(b.x) + 0x8000u, u5 = __float_as_uint(b.y) + 0x8000u;
    uint32_t u6 = __float_as_uint(b.z) + 0x8000u, u7 = __float_as_uint(b.w) + 0x8000u;
    union { uint32_t w[4]; bfrag8 r; } u;
    u.w[0] = __builtin_amdgcn_perm(u1, u0, 0x07060302u);
    u.w[1] = __builtin_amdgcn_perm(u3, u2, 0x07060302u);
    u.w[2] = __builtin_amdgcn_perm(u5, u4, 0x07060302u);
    u.w[3] = __builtin_amdgcn_perm(u7, u6, 0x07060302u);
    return u.r;
}

// Weights fp32->bf16: blocks [0,128) Wq, [128,256) Wk, [256,384) Wv, [384,640) Wo.
__global__ __launch_bounds__(256) void convert_w(
    const float* __restrict__ Wq, const float* __restrict__ Wk,
    const float* __restrict__ Wv, const float* __restrict__ Wo,
    uint16_t* __restrict__ q, uint16_t* __restrict__ k,
    uint16_t* __restrict__ v, uint16_t* __restrict__ o)
{
    int zz = blockIdx.x;
    const float* src; uint16_t* dst; size_t off;
    if      (zz < 128) { src = Wq; dst = q; off = (size_t)zz * 2048; }
    else if (zz < 256) { src = Wk; dst = k; off = (size_t)(zz - 128) * 2048; }
    else if (zz < 384) { src = Wv; dst = v; off = (size_t)(zz - 256) * 2048; }
    else               { src = Wo; dst = o; off = (size_t)(zz - 384) * 2048; }
    size_t i = off + (size_t)threadIdx.x * 8;
    float4 a = *(const float4*)&src[i];
    float4 b = *(const float4*)&src[i + 4];
    *(bfrag8*)&dst[i] = cvt8perm(a, b);
}

// ---------------------------------------------------------------------------
// 128x128-tile bf16 GEMM, double-buffered LDS (R9-verified), templated on
// whether A is fp32 (converted inline at stage time) or bf16.
// ---------------------------------------------------------------------------
template <int AF32>
__device__ __forceinline__ void gemm128T(
    const void* __restrict__ A, int lda,
    const uint16_t* __restrict__ B, int ldb,
    void* __restrict__ C, int ldc, int cF32,
    const float* __restrict__ bias, float scale,
    int Kd, int m0, int n0)
{
    __shared__ __align__(16) uint16_t As[2][128 * 40];
    __shared__ __align__(16) uint16_t Bs[2][128 * 40];

    const int tid  = threadIdx.x;
    const int lane = tid & 63;
    const int wv   = tid >> 6;
    const int lo   = lane & 15;
    const int quad = lane >> 4;
    const int srow = tid >> 2;
    const int skq  = (tid & 3) * 8;
    const int rb   = (wv >> 1) * 64;
    const int cb   = (wv & 1) * 64;

    const facc4 ZACC = {0.f, 0.f, 0.f, 0.f};
    facc4 acc[4][4];
#pragma unroll
    for (int i = 0; i < 4; ++i)
#pragma unroll
        for (int j = 0; j < 4; ++j) acc[i][j] = ZACC;

    const float*    fA0 = AF32 ? &((const float*)A)[(size_t)(m0 + srow) * lda + skq] : nullptr;
    const float*    fA1 = AF32 ? &((const float*)A)[(size_t)(m0 + srow + 64) * lda + skq] : nullptr;
    const uint16_t* hA0 = AF32 ? nullptr : &((const uint16_t*)A)[(size_t)(m0 + srow) * lda + skq];
    const uint16_t* hA1 = AF32 ? nullptr : &((const uint16_t*)A)[(size_t)(m0 + srow + 64) * lda + skq];
    const uint16_t* pB0 = &B[(size_t)(n0 + srow) * ldb + skq];
    const uint16_t* pB1 = &B[(size_t)(n0 + srow + 64) * ldb + skq];

    bfrag8 ra0, ra1;
    float4 f0a, f0b, f1a, f1b;
    if (AF32) {
        f0a = *(const float4*)fA0; f0b = *(const float4*)(fA0 + 4);
        f1a = *(const float4*)fA1; f1b = *(const float4*)(fA1 + 4);
    } else {
        ra0 = *(const bfrag8*)hA0;
        ra1 = *(const bfrag8*)hA1;
    }
    bfrag8 rb0 = *(const bfrag8*)pB0;
    bfrag8 rb1 = *(const bfrag8*)pB1;

    if (AF32) {
        *(bfrag8*)&As[0][srow * 40 + skq]        = cvt8perm(f0a, f0b);
        *(bfrag8*)&As[0][(srow + 64) * 40 + skq] = cvt8perm(f1a, f1b);
    } else {
        *(bfrag8*)&As[0][srow * 40 + skq]        = ra0;
        *(bfrag8*)&As[0][(srow + 64) * 40 + skq] = ra1;
    }
    *(bfrag8*)&Bs[0][srow * 40 + skq]        = rb0;
    *(bfrag8*)&Bs[0][(srow + 64) * 40 + skq] = rb1;
    __syncthreads();

    int p = 0;
    for (int kt = 0; kt < Kd; kt += 32) {
        const bool more = (kt + 32 < Kd);
        if (more) {  // fire-and-forget prefetch of next K-slab
            if (AF32) {
                f0a = *(const float4*)(fA0 + kt + 32); f0b = *(const float4*)(fA0 + kt + 36);
                f1a = *(const float4*)(fA1 + kt + 32); f1b = *(const float4*)(fA1 + kt + 36);
            } else {
                ra0 = *(const bfrag8*)(hA0 + kt + 32);
                ra1 = *(const bfrag8*)(hA1 + kt + 32);
            }
            rb0 = *(const bfrag8*)(pB0 + kt + 32);
            rb1 = *(const bfrag8*)(pB1 + kt + 32);
        }

        bfrag8 af[4], bf[4];
#pragma unroll
        for (int i = 0; i < 4; ++i) {
            af[i] = *(const bfrag8*)&As[p][(rb + i * 16 + lo) * 40 + quad * 8];
            bf[i] = *(const bfrag8*)&Bs[p][(cb + i * 16 + lo) * 40 + quad * 8];
        }
#pragma unroll
        for (int i = 0; i < 4; ++i)
#pragma unroll
            for (int j = 0; j < 4; ++j)
                acc[i][j] = MFMA_BF16(af[i], bf[j], acc[i][j]);

        if (more) {
            if (AF32) {
                *(bfrag8*)&As[1 - p][srow * 40 + skq]        = cvt8perm(f0a, f0b);
                *(bfrag8*)&As[1 - p][(srow + 64) * 40 + skq] = cvt8perm(f1a, f1b);
            } else {
                *(bfrag8*)&As[1 - p][srow * 40 + skq]        = ra0;
                *(bfrag8*)&As[1 - p][(srow + 64) * 40 + skq] = ra1;
            }
            *(bfrag8*)&Bs[1 - p][srow * 40 + skq]        = rb0;
            *(bfrag8*)&Bs[1 - p][(srow + 64) * 40 + skq] = rb1;
            __syncthreads();  // the only barrier per iter
            p ^= 1;
        }
    }

#pragma unroll
    for (int j = 0; j < 4; ++j) {
        int col  = n0 + cb + j * 16 + lo;
        float bv = bias ? bias[col] : 0.f;
#pragma unroll
        for (int i = 0; i < 4; ++i) {
#pragma unroll
            for (int r = 0; r < 4; ++r) {
                int row = m0 + rb + i * 16 + quad * 4 + r;
                float v = acc[i][j][r] * scale + bv;
                if (cF32) ((float*)C)[(size_t)row * ldc + col] = v;
                else      ((uint16_t*)C)[(size_t)row * ldc + col] = f2b(v);
            }
        }
    }
}

#define SC_Q (0.125f * 1.4426950408889634f)  // softmax scale * log2(e), folded into Q

// QKV from fp32 x directly (left half via lda=DMODEL, cols < 512 only).
__global__ __launch_bounds__(256, 2) void qkv_kernel(
    const float* __restrict__ x,
    const uint16_t* __restrict__ Wqb, const uint16_t* __restrict__ Wkb,
    const uint16_t* __restrict__ Wvb,
    uint16_t* __restrict__ Q, uint16_t* __restrict__ K, uint16_t* __restrict__ V)
{
    const int z = blockIdx.z;
    const uint16_t* W = (z == 0) ? Wqb : (z == 1) ? Wkb : Wvb;
    uint16_t* Out     = (z == 0) ? Q   : (z == 1) ? K   : V;
    float scale       = (z == 0) ? SC_Q : 1.0f;
    gemm128T<1>(x, DMODEL, W, DHALF, Out, DHALF, 0, nullptr, scale, DHALF,
                blockIdx.y * 128, blockIdx.x * 128);
}

__global__ __launch_bounds__(256, 2) void outproj_kernel(
    const uint16_t* __restrict__ O, const uint16_t* __restrict__ Wob,
    const float* __restrict__ bo, float* __restrict__ Y)
{
    gemm128T<0>(O, DHALF, Wob, DHALF, Y, DMODEL, 1, bo, 1.0f, DHALF,
                blockIdx.y * 128, blockIdx.x * 128);
}

// ---------------------------------------------------------------------------
// Split-K flash attention (R8 q-partitioning + R11 ones-column l).
// R13: K a-fragments loaded DIRECTLY from global (same 4KB tile per wave ->
// L1 broadcast); Ks LDS tile deleted (-60 DS cyc/wave/tile, LDS 18.4->13.3KB).
// Register prefetch of next tile's kf[4] + vreg keeps latency covered.
// ---------------------------------------------------------------------------
__global__ __launch_bounds__(256) void attn_kernel(
    const uint16_t* __restrict__ Q, const uint16_t* __restrict__ Kb,
    const uint16_t* __restrict__ Vb, uint16_t* __restrict__ Op,
    float* __restrict__ lbuf, int kspan)
{
    __shared__ __align__(16) uint16_t Vt[32 * 64];     // V^T [d][key], swizzled
    __shared__ __align__(16) uint16_t Ps[4 * 16 * 72]; // per-wave P [q][key]

    const int tid  = threadIdx.x;
    const int lane = tid & 63;
    const int wv   = tid >> 6;
    const int lo   = lane & 15;
    const int quad = lane >> 4;
    const int h    = blockIdx.y;
    const int q0   = blockIdx.x * 64;
    const int sp   = blockIdx.z;
    const int srow = tid >> 2;
    const int skq  = (tid & 3) * 8;

    const facc4 ZACC = {0.f, 0.f, 0.f, 0.f};

    const bfrag8 qf = *(const bfrag8*)&Q[(size_t)(q0 + wv * 16 + lo) * DHALF + h * DH + quad * 8];

    bfrag8 ones;
#pragma unroll
    for (int j = 0; j < 8; ++j) ones[j] = (short)0x3F80;  // bf16 1.0

    int vt_w[8];
#pragma unroll
    for (int j = 0; j < 8; ++j) {
        int d  = skq + j;
        int Rd = ((d & 7) + 2 * (d >> 3)) & 7;
        vt_w[j] = d * 64 + ((((srow >> 3) + Rd) & 7) << 3) + (srow & 7);
    }
    int vt_r[2][2];
#pragma unroll
    for (int dt = 0; dt < 2; ++dt) {
        int d  = dt * 16 + lo;
        int Rd = ((d & 7) + 2 * (d >> 3)) & 7;
#pragma unroll
        for (int c = 0; c < 2; ++c)
            vt_r[c][dt] = d * 64 + ((((c * 4 + quad) + Rd) & 7) << 3);
    }
    const int pbase = wv * (16 * 72);
    const int ps_w  = pbase + lo * 72 + 4 * quad;
    const int ps_r  = pbase + lo * 72 + quad * 8;

    // K a-fragment base: row key = kb + 16t + lo, cols quad*8..quad*8+7
    const uint16_t* pKf = &Kb[(size_t)lo * DHALF + h * DH + quad * 8];
    const uint16_t* pV  = &Vb[(size_t)srow * DHALF + h * DH + skq];

    facc4 oacc[2], oaccL;
    oacc[0] = ZACC; oacc[1] = ZACC; oaccL = ZACC;

    const int kb0  = sp * kspan;
    const int kend = kb0 + kspan;

    bfrag8 kf[4], kf2[4];
#pragma unroll
    for (int t = 0; t < 4; ++t)
        kf[t] = *(const bfrag8*)(pKf + (size_t)(kb0 + t * 16) * DHALF);
    float4 vreg = *(const float4*)(pV + (size_t)kb0 * DHALF);

    for (int kb = kb0; kb < kend; kb += 64) {
        {
            const uint16_t* vp = (const uint16_t*)&vreg;
#pragma unroll
            for (int j = 0; j < 8; ++j) Vt[vt_w[j]] = vp[j];
        }
        __syncthreads();

        const bool more = (kb + 64 < kend);
        if (more) {  // fire-and-forget prefetch of next K/V tile
            vreg = *(const float4*)(pV + (size_t)(kb + 64) * DHALF);
#pragma unroll
            for (int t = 0; t < 4; ++t)
                kf2[t] = *(const bfrag8*)(pKf + (size_t)(kb + 64 + t * 16) * DHALF);
        }

#pragma unroll
        for (int t = 0; t < 4; ++t) {
            facc4 s = MFMA_BF16(kf[t], qf, ZACC);  // D[key=16t+4q+r][q=lo], pre-scaled
            float p0 = __builtin_amdgcn_exp2f(s[0]);
            float p1 = __builtin_amdgcn_exp2f(s[1]);
            float p2 = __builtin_amdgcn_exp2f(s[2]);
            float p3 = __builtin_amdgcn_exp2f(s[3]);
            uint32_t u0 = __float_as_uint(p0) + 0x8000u;
            uint32_t u1 = __float_as_uint(p1) + 0x8000u;
            uint32_t u2 = __float_as_uint(p2) + 0x8000u;
            uint32_t u3 = __float_as_uint(p3) + 0x8000u;
            uint2 w;
            w.x = __builtin_amdgcn_perm(u1, u0, 0x07060302u);
            w.y = __builtin_amdgcn_perm(u3, u2, 0x07060302u);
            *(uint2*)&Ps[ps_w + 16 * t] = w;  // single ds_write_b64
        }
        __builtin_amdgcn_wave_barrier();  // Ps is same-wave-only; pin DS order

#pragma unroll
        for (int c = 0; c < 2; ++c) {
            bfrag8 pf = *(const bfrag8*)&Ps[ps_r + c * 32];
#pragma unroll
            for (int dt = 0; dt < 2; ++dt) {
                bfrag8 vf = *(const bfrag8*)&Vt[vt_r[c][dt]];
                oacc[dt] = MFMA_BF16(pf, vf, oacc[dt]);
            }
            oaccL = MFMA_BF16(pf, ones, oaccL);  // l: D[q][*] = sum_k P[q][k]
        }
        __syncthreads();  // protect Vt restage

        if (more) {
#pragma unroll
            for (int t = 0; t < 4; ++t) kf[t] = kf2[t];
        }
    }

    if (lo == 0) {
#pragma unroll
        for (int r = 0; r < 4; ++r)
            lbuf[((size_t)sp * NH + h) * SEQ + q0 + wv * 16 + quad * 4 + r] = oaccL[r];
    }

    uint16_t* Od = Op + (size_t)sp * SEQ * DHALF;
#pragma unroll
    for (int r = 0; r < 4; ++r) {
        int row = q0 + wv * 16 + quad * 4 + r;
        Od[(size_t)row * DHALF + h * DH + lo]      = f2b(oacc[0][r]);  // unnormalized
        Od[(size_t)row * DHALF + h * DH + 16 + lo] = f2b(oacc[1][r]);
    }
}

// O = sum_sp(Op_sp) / sum_sp(l_sp); 1 thread = 8 cols (within one head).
__global__ __launch_bounds__(256) void combine_kernel(
    const uint16_t* __restrict__ Op, const float* __restrict__ lbuf,
    uint16_t* __restrict__ O, int ns)
{
    int t   = blockIdx.x * 256 + threadIdx.x;
    int row = t >> 6;
    int cb  = (t & 63) << 3;
    int h   = cb >> 5;
    float l = 0.f;
    float acc[8] = {0.f, 0.f, 0.f, 0.f, 0.f, 0.f, 0.f, 0.f};
    for (int sp = 0; sp < ns; ++sp) {
        l += lbuf[((size_t)sp * NH + h) * SEQ + row];
        bfrag8 a = *(const bfrag8*)&Op[(size_t)sp * SEQ * DHALF + (size_t)row * DHALF + cb];
#pragma unroll
        for (int j = 0; j < 8; ++j) acc[j] += b2f((uint16_t)a[j]);
    }
    float inv = 1.0f / l;
    bfrag8 o;
#pragma unroll
    for (int j = 0; j < 8; ++j) o[j] = (short)f2b(acc[j] * inv);
    *(bfrag8*)&O[(size_t)row * DHALF + cb] = o;
}

extern "C" void kernel_launch(void* const* d_in, const int* in_sizes, int n_in,
                              void* d_out, int out_size, void* d_ws, size_t ws_size,
                              hipStream_t stream)
{
    const float* x  = (const float*)d_in[0];
    const float* Wq = (const float*)d_in[1];
    const float* Wk = (const float*)d_in[2];
    const float* Wv = (const float*)d_in[3];
    const float* Wo = (const float*)d_in[4];
    const float* bo = (const float*)d_in[5];

    // ws (u16 elems): Wqb/Wkb/Wvb 256K ea | Wob 512K | Q,K,V,O 2M ea | Op ns*2M
    // then lbuf (ns*NH*SEQ fp32). ns=4 needs ~37.3 MB; fall back to 2 if short.
    size_t fixed_e = 3 * (size_t)DHALF * DHALF + (size_t)DMODEL * DHALF
                   + 4 * (size_t)SEQ * DHALF;
    size_t need4 = (fixed_e + 4 * (size_t)SEQ * DHALF) * 2
                 + 4 * (size_t)NH * SEQ * 4;
    const int ns = (ws_size >= need4) ? 4 : 2;

    uint16_t* Wqb = (uint16_t*)d_ws;
    uint16_t* Wkb = Wqb + (size_t)DHALF * DHALF;
    uint16_t* Wvb = Wkb + (size_t)DHALF * DHALF;
    uint16_t* Wob = Wvb + (size_t)DHALF * DHALF;
    uint16_t* Q   = Wob + (size_t)DMODEL * DHALF;
    uint16_t* K   = Q + (size_t)SEQ * DHALF;
    uint16_t* V   = K + (size_t)SEQ * DHALF;
    uint16_t* O   = V + (size_t)SEQ * DHALF;
    uint16_t* Op  = O + (size_t)SEQ * DHALF;
    float*  lbuf  = (float*)(Op + (size_t)ns * SEQ * DHALF);

    convert_w<<<640, 256, 0, stream>>>(Wq, Wk, Wv, Wo, Wqb, Wkb, Wvb, Wob);
    qkv_kernel<<<dim3(DHALF / 128, SEQ / 128, 3), 256, 0, stream>>>(
        x, Wqb, Wkb, Wvb, Q, K, V);
    attn_kernel<<<dim3(SEQ / 64, NH, ns), 256, 0, stream>>>(Q, K, V, Op, lbuf, SEQ / ns);
    combine_kernel<<<1024, 256, 0, stream>>>(Op, lbuf, O, ns);
    outproj_kernel<<<dim3(DMODEL / 128, SEQ / 128), 256, 0, stream>>>(
        O, Wob, bo, (float*)d_out);
}